// Round 1
// baseline (206.575 us; speedup 1.0000x reference)
//
#include <hip/hip_runtime.h>
#include <hip/hip_bf16.h>

// VQ-VAE quantizer, MI355X.
// latents: [B=32, D=64, H=64, W=64] fp32 ; embedding: [K=512, D=64] fp32
// out: quantized [B,D,H,W] fp32 (8388608 floats) then vq_loss scalar (1 float).
// Forward facts: quantized_st == quantized; vq_loss = 1.25 * mean((q - lat)^2).

#define VQ_K 512
#define VQ_D 64
#define VQ_HW 4096           // 64*64
#define VQ_N 131072          // 32*4096 pixels
#define VQ_ELEMS 8388608     // N*D

__global__ __launch_bounds__(256) void vq_quantize_kernel(
    const float* __restrict__ lat,   // [B, D, H, W]
    const float* __restrict__ emb,   // [K, D]
    float* __restrict__ out,         // [B, D, H, W]
    float* __restrict__ partial)     // [gridDim.x] loss partial sums
{
    __shared__ float e2[VQ_K];       // ||e_k||^2
    const int tid = threadIdx.x;

    // Each of 256 threads computes 2 of the 512 squared norms.
    for (int k = tid; k < VQ_K; k += 256) {
        float s = 0.f;
        #pragma unroll
        for (int d = 0; d < VQ_D; ++d) {
            float v = emb[k * VQ_D + d];
            s = fmaf(v, v, s);
        }
        e2[k] = s;
    }
    __syncthreads();

    // One thread per pixel (b, h, w). Consecutive lanes -> consecutive w:
    // loads of lat[b, d, h, w+lane] are coalesced for each d.
    const int p  = blockIdx.x * 256 + tid;
    const int b  = p >> 12;          // / 4096
    const int hw = p & 4095;
    const float* latp = lat + (size_t)b * (VQ_D * VQ_HW) + hw;

    float x[VQ_D];
    #pragma unroll
    for (int d = 0; d < VQ_D; ++d) x[d] = latp[d * VQ_HW];

    // Argmin over codes: score_k = ||e_k||^2 - 2 * <x, e_k>   (||x||^2 constant)
    // k is wave-uniform -> emb reads scalarize to s_load; inner loop is
    // v_fmac_f32 with SGPR operand. 2 codes x 2 accumulators for ILP.
    float best = 3.4e38f;
    int bestk = 0;
    for (int k = 0; k < VQ_K; k += 2) {
        const float* e0 = emb + k * VQ_D;
        const float* e1 = e0 + VQ_D;
        float a00 = 0.f, a01 = 0.f, a10 = 0.f, a11 = 0.f;
        #pragma unroll
        for (int d = 0; d < VQ_D; d += 2) {
            a00 = fmaf(e0[d],     x[d],     a00);
            a01 = fmaf(e0[d + 1], x[d + 1], a01);
            a10 = fmaf(e1[d],     x[d],     a10);
            a11 = fmaf(e1[d + 1], x[d + 1], a11);
        }
        float s0 = e2[k]     - 2.f * (a00 + a01);
        float s1 = e2[k + 1] - 2.f * (a10 + a11);
        if (s0 < best) { best = s0; bestk = k; }
        if (s1 < best) { best = s1; bestk = k + 1; }
    }

    // Gather winning code, write output (coalesced per d), accumulate loss.
    const float* q = emb + bestk * VQ_D;
    float* outp = out + (size_t)b * (VQ_D * VQ_HW) + hw;
    float lsum = 0.f;
    #pragma unroll
    for (int d = 0; d < VQ_D; ++d) {
        float qd = q[d];
        float diff = qd - x[d];
        lsum = fmaf(diff, diff, lsum);
        outp[d * VQ_HW] = qd;
    }

    // Wave reduce (64 lanes) then cross-wave via LDS; one partial per block.
    #pragma unroll
    for (int off = 32; off > 0; off >>= 1)
        lsum += __shfl_down(lsum, off, 64);

    __shared__ float wsum[4];
    const int lane = tid & 63, wid = tid >> 6;
    if (lane == 0) wsum[wid] = lsum;
    __syncthreads();
    if (tid == 0)
        partial[blockIdx.x] = wsum[0] + wsum[1] + wsum[2] + wsum[3];
}

__global__ __launch_bounds__(64) void vq_loss_kernel(
    const float* __restrict__ partial,  // [512]
    float* __restrict__ loss_out)       // &out[VQ_ELEMS]
{
    const int tid = threadIdx.x;
    float s = 0.f;
    #pragma unroll
    for (int i = 0; i < 8; ++i) s += partial[tid + i * 64];
    #pragma unroll
    for (int off = 32; off > 0; off >>= 1)
        s += __shfl_down(s, off, 64);
    if (tid == 0)
        *loss_out = 1.25f * s / (float)VQ_ELEMS;  // (beta + 1) * mean
}

extern "C" void kernel_launch(void* const* d_in, const int* in_sizes, int n_in,
                              void* d_out, int out_size, void* d_ws, size_t ws_size,
                              hipStream_t stream) {
    const float* lat = (const float*)d_in[0];   // 32*64*64*64
    const float* emb = (const float*)d_in[1];   // 512*64
    float* out = (float*)d_out;                 // 8388608 + 1
    float* partial = (float*)d_ws;              // 512 floats of scratch

    vq_quantize_kernel<<<VQ_N / 256, 256, 0, stream>>>(lat, emb, out, partial);
    vq_loss_kernel<<<1, 64, 0, stream>>>(partial, out + (size_t)VQ_ELEMS);
}

// Round 2
// 103.704 us; speedup vs baseline: 1.9920x; 1.9920x over previous
//
#include <hip/hip_runtime.h>
#include <hip/hip_bf16.h>

// VQ-VAE quantizer, MI355X, bf16-MFMA distance GEMM.
// latents: [B=32, D=64, H=64, W=64] fp32 ; embedding: [K=512, D=64] fp32
// out: quantized [B,D,H,W] fp32 (8388608) then vq_loss scalar (1).
// loss = 1.25 * mean(||x - q||^2) = 1.25 * mean_per_elem(||x||^2 + (e2 - 2 x.e_best))

#define VQ_K 512
#define VQ_D 64
#define VQ_HW 4096
#define VQ_N 131072
#define VQ_ELEMS 8388608

typedef float f32x4 __attribute__((ext_vector_type(4)));
typedef __bf16 bf16x8 __attribute__((ext_vector_type(8)));

// ws layout (bytes):
//   [0,      65536) : codebook bf16 in B-fragment order (64 chunks of 1 KB)
//   [65536,  67584) : e2p[512] = ||e_k||^2 + 0.5
//   [67584,  69632) : loss partials[512]

__device__ __forceinline__ void gl_lds16(const void* g, void* l) {
  __builtin_amdgcn_global_load_lds(
      (const __attribute__((address_space(1))) void*)g,
      (__attribute__((address_space(3))) void*)l, 16, 0, 0);
}

// ---- prep: bf16 codebook fragments + squared norms -------------------------
__global__ __launch_bounds__(256) void vq_prep(
    const float* __restrict__ emb, uint32_t* __restrict__ bfrag,
    float* __restrict__ e2p)
{
  const int tid = threadIdx.x;
  if (blockIdx.x < 16) {
    // one 16-B fragment chunk per thread: chunk id = ct*2+kh (64) x lane (64)
    const int gid  = blockIdx.x * 256 + tid;     // 0..4095
    const int lane = gid & 63, ckh = gid >> 6;   // ckh = ct*2 + kh
    const int ct = ckh >> 1, kh = ckh & 1;
    const int code  = ct * 16 + (lane & 15);     // B-frag: n = lane&15
    const int dbase = kh * 32 + (lane >> 4) * 8; // k = kh*32 + quad*8 + j
    const float* src = emb + code * VQ_D + dbase;
    uint32_t wds[4];
    #pragma unroll
    for (int jj = 0; jj < 4; ++jj) {
      float2 f2; f2.x = src[2 * jj]; f2.y = src[2 * jj + 1];
      __hip_bfloat162 bb = __float22bfloat162_rn(f2);
      wds[jj] = *(const uint32_t*)&bb;
    }
    uint4 v; v.x = wds[0]; v.y = wds[1]; v.z = wds[2]; v.w = wds[3];
    *(uint4*)&bfrag[gid * 4] = v;
  } else {
    for (int cc = tid; cc < VQ_K; cc += 256) {
      const float* src = emb + cc * VQ_D;
      float s = 0.f;
      #pragma unroll
      for (int d = 0; d < VQ_D; ++d) s = fmaf(src[d], src[d], s);
      e2p[cc] = s + 0.5f;   // +0.5 keeps all packed scores positive
    }
  }
}

// ---- main: MFMA scores + packed argmin + gather/write + loss ---------------
__global__ __launch_bounds__(256) void vq_main(
    const float* __restrict__ lat, const float* __restrict__ emb,
    const uint32_t* __restrict__ bfrag_g, const float* __restrict__ e2p_g,
    float* __restrict__ out, float* __restrict__ partial)
{
  __shared__ __align__(16) uint32_t a_frag[8192];  // 32 KB: 16 rt x 2 kh x 64 lanes x 16 B
  __shared__ __align__(16) uint32_t b_frag[8192];  // 32 KB: one 256-code half
  __shared__ float    e2p[VQ_K];
  __shared__ uint32_t bestp[256];
  __shared__ float    wred[4];

  const int tid  = threadIdx.x;
  const int lane = tid & 63;
  const int w    = tid >> 6;

  // async-stage pass-0 B fragments (32 KB, 8 x 1KB chunks per wave)
  {
    const char* src = (const char*)bfrag_g;
    char* dst = (char*)b_frag;
    #pragma unroll
    for (int i = 0; i < 8; ++i) {
      const int c = i * 4 + w;
      gl_lds16(src + c * 1024 + lane * 16, dst + c * 1024 + lane * 16);
    }
  }
  e2p[tid]       = e2p_g[tid];
  e2p[tid + 256] = e2p_g[tid + 256];

  // stage X tile (256 pixels x 64 dims) -> LDS in A-fragment order; fp32 ||x||^2
  const int bimg = blockIdx.x >> 4;        // 16 blocks per image (4096/256)
  const int hw0  = (blockIdx.x & 15) << 8;
  const float* latb = lat + (size_t)bimg * (VQ_D * VQ_HW) + hw0;
  float x2 = 0.f;
  {
    const int rt = tid >> 4, ll = tid & 15;
    #pragma unroll
    for (int i = 0; i < 32; ++i) {
      const int d0 = i * 2;
      const float v0 = latb[(d0    ) * VQ_HW + tid];
      const float v1 = latb[(d0 + 1) * VQ_HW + tid];
      x2 = fmaf(v0, v0, fmaf(v1, v1, x2));
      float2 f2; f2.x = v0; f2.y = v1;
      __hip_bfloat162 bb = __float22bfloat162_rn(f2);
      const int kh = d0 >> 5, quad = (d0 >> 3) & 3, j = d0 & 7;
      const int lf = quad * 16 + ll;       // A-frag: m = lane&15, k = quad*8+j
      a_frag[(((rt * 2 + kh) * 64 + lf) * 16 + j * 2) >> 2] = *(const uint32_t*)&bb;
    }
  }
  __syncthreads();   // drains global_load_lds (vmcnt) + LDS writes

  // resident A fragments: 4 row-tiles (64 pixels) per wave
  bf16x8 af[4][2];
  #pragma unroll
  for (int rt = 0; rt < 4; ++rt)
    #pragma unroll
    for (int kh = 0; kh < 2; ++kh)
      af[rt][kh] = *(const bf16x8*)&a_frag[(((w * 4 + rt) * 2 + kh) * 64 + lane) * 4];

  float mins[4][4];
  #pragma unroll
  for (int rt = 0; rt < 4; ++rt)
    #pragma unroll
    for (int r = 0; r < 4; ++r) mins[rt][r] = 3.0e38f;

  const int lane15 = lane & 15;

  for (int h = 0; h < 2; ++h) {
    if (h == 1) {               // swap in the second 256 codes
      __syncthreads();
      const char* src = (const char*)bfrag_g + 32768;
      char* dst = (char*)b_frag;
      #pragma unroll
      for (int i = 0; i < 8; ++i) {
        const int c = i * 4 + w;
        gl_lds16(src + c * 1024 + lane * 16, dst + c * 1024 + lane * 16);
      }
      __syncthreads();
    }
    for (int ctp = 0; ctp < 16; ++ctp) {
      const int code0 = h * 256 + ctp * 16;
      const float e2v = e2p[code0 + lane15];          // ||e||^2 + 0.5, this lane's col
      const uint32_t ucode = (uint32_t)(code0 + lane15);
      const bf16x8 b0 = *(const bf16x8*)&b_frag[((ctp * 2 + 0) * 64 + lane) * 4];
      const bf16x8 b1 = *(const bf16x8*)&b_frag[((ctp * 2 + 1) * 64 + lane) * 4];
      f32x4 acc[4];
      #pragma unroll
      for (int rt = 0; rt < 4; ++rt) {
        acc[rt] = (f32x4)(0.f);
        acc[rt] = __builtin_amdgcn_mfma_f32_16x16x32_bf16(af[rt][0], b0, acc[rt], 0, 0, 0);
        acc[rt] = __builtin_amdgcn_mfma_f32_16x16x32_bf16(af[rt][1], b1, acc[rt], 0, 0, 0);
      }
      // score = (e2+0.5) - 2*dot > 0; pack code into 9 mantissa LSBs; float-min
      #pragma unroll
      for (int rt = 0; rt < 4; ++rt)
        #pragma unroll
        for (int r = 0; r < 4; ++r) {
          const float s = fmaf(-2.f, acc[rt][r], e2v);
          const uint32_t pk = (__float_as_uint(s) & 0xFFFFFE00u) | ucode;
          mins[rt][r] = fminf(mins[rt][r], __uint_as_float(pk));
        }
    }
  }

  // argmin across the 16 columns of each quad (C: col=lane&15, row=quad*4+r)
  #pragma unroll
  for (int off = 1; off < 16; off <<= 1)
    #pragma unroll
    for (int rt = 0; rt < 4; ++rt)
      #pragma unroll
      for (int r = 0; r < 4; ++r) {
        const float o = __shfl_xor(mins[rt][r], off, 64);
        mins[rt][r] = fminf(mins[rt][r], o);
      }
  const int quad = lane >> 4;
  if (lane15 == 0) {
    #pragma unroll
    for (int rt = 0; rt < 4; ++rt)
      #pragma unroll
      for (int r = 0; r < 4; ++r)
        bestp[(w * 4 + rt) * 16 + quad * 4 + r] = __float_as_uint(mins[rt][r]);
  }
  __syncthreads();

  // per-pixel: unpack code + min score; write quantized (coalesced per d)
  const uint32_t u = bestp[tid];
  const int code = (int)(u & 511u);
  const float smin = __uint_as_float(u & 0xFFFFFE00u) - 0.5f;
  float lossc = x2 + smin;                 // ||x - q||^2 for this pixel

  const float* q = emb + code * VQ_D;      // L1-hot gather (emb = 128 KB)
  float* outp = out + (size_t)bimg * (VQ_D * VQ_HW) + hw0 + tid;
  #pragma unroll
  for (int d = 0; d < VQ_D; ++d) outp[d * VQ_HW] = q[d];

  #pragma unroll
  for (int off = 32; off > 0; off >>= 1) lossc += __shfl_down(lossc, off, 64);
  if (lane == 0) wred[w] = lossc;
  __syncthreads();
  if (tid == 0) partial[blockIdx.x] = wred[0] + wred[1] + wred[2] + wred[3];
}

__global__ __launch_bounds__(64) void vq_loss_kernel(
    const float* __restrict__ partial, float* __restrict__ loss_out)
{
  const int tid = threadIdx.x;
  float s = 0.f;
  #pragma unroll
  for (int i = 0; i < 8; ++i) s += partial[tid + i * 64];
  #pragma unroll
  for (int off = 32; off > 0; off >>= 1) s += __shfl_down(s, off, 64);
  if (tid == 0) *loss_out = 1.25f * s / (float)VQ_ELEMS;
}

extern "C" void kernel_launch(void* const* d_in, const int* in_sizes, int n_in,
                              void* d_out, int out_size, void* d_ws, size_t ws_size,
                              hipStream_t stream) {
  const float* lat = (const float*)d_in[0];
  const float* emb = (const float*)d_in[1];
  float* out = (float*)d_out;

  uint32_t* bfrag = (uint32_t*)d_ws;
  float* e2p      = (float*)((char*)d_ws + 65536);
  float* partial  = (float*)((char*)d_ws + 67584);

  vq_prep<<<17, 256, 0, stream>>>(emb, bfrag, e2p);
  vq_main<<<VQ_N / 256, 256, 0, stream>>>(lat, emb, bfrag, e2p, out, partial);
  vq_loss_kernel<<<1, 64, 0, stream>>>(partial, out + (size_t)VQ_ELEMS);
}

// Round 3
// 103.697 us; speedup vs baseline: 1.9921x; 1.0001x over previous
//
#include <hip/hip_runtime.h>
#include <hip/hip_bf16.h>

// VQ-VAE quantizer, MI355X, bf16-MFMA distance GEMM, barrier-free K-loop.
// latents: [B=32, D=64, H=64, W=64] fp32 ; embedding: [K=512, D=64] fp32
// out: quantized [B,D,H,W] fp32 (8388608) then vq_loss scalar (1).
// loss = 1.25 * mean(||x||^2 + (||e||^2 - 2 x.e_best))

#define VQ_K 512
#define VQ_D 64
#define VQ_HW 4096
#define VQ_N 131072
#define VQ_ELEMS 8388608

typedef float f32x4 __attribute__((ext_vector_type(4)));
typedef __bf16 bf16x8 __attribute__((ext_vector_type(8)));

// ws layout (bytes):
//   [0,      65536) : codebook bf16 in B-fragment order (64 chunks of 1 KB)
//   [65536,  67584) : e2p[512] = ||e_k||^2 + 0.5
//   [67584,  69632) : loss partials[512]

// ---- prep: bf16 codebook fragments + squared norms -------------------------
__global__ __launch_bounds__(256) void vq_prep(
    const float* __restrict__ emb, uint32_t* __restrict__ bfrag,
    float* __restrict__ e2p)
{
  const int tid = threadIdx.x;
  if (blockIdx.x < 16) {
    // one 16-B fragment chunk per thread: chunk id = (ct*2+kh) (64) x lane (64)
    const int gid  = blockIdx.x * 256 + tid;     // 0..4095
    const int lane = gid & 63, ckh = gid >> 6;
    const int ct = ckh >> 1, kh = ckh & 1;
    const int code  = ct * 16 + (lane & 15);     // B-frag: n = lane&15
    const int dbase = kh * 32 + (lane >> 4) * 8; // k = kh*32 + quad*8 + j
    const float* src = emb + code * VQ_D + dbase;
    uint32_t wds[4];
    #pragma unroll
    for (int jj = 0; jj < 4; ++jj) {
      float2 f2; f2.x = src[2 * jj]; f2.y = src[2 * jj + 1];
      __hip_bfloat162 bb = __float22bfloat162_rn(f2);
      wds[jj] = *(const uint32_t*)&bb;
    }
    uint4 v; v.x = wds[0]; v.y = wds[1]; v.z = wds[2]; v.w = wds[3];
    *(uint4*)&bfrag[gid * 4] = v;
  } else {
    for (int cc = tid; cc < VQ_K; cc += 256) {
      const float* src = emb + cc * VQ_D;
      float s = 0.f;
      #pragma unroll
      for (int d = 0; d < VQ_D; ++d) s = fmaf(src[d], src[d], s);
      e2p[cc] = s + 0.5f;   // +0.5 keeps all packed scores positive
    }
  }
}

// ---- main: MFMA scores + packed argmin + gather/write + loss ---------------
__global__ __launch_bounds__(256, 3) void vq_main(
    const float* __restrict__ lat, const float* __restrict__ emb,
    const uint32_t* __restrict__ bfrag_g, const float* __restrict__ e2p_g,
    float* __restrict__ out, float* __restrict__ partial)
{
  __shared__ __align__(16) uint32_t a_frag[8192];  // 32 KB: 16 rt x 2 kh x 64 lanes x 16 B
  __shared__ float    e2s[VQ_K];                   // 2 KB
  __shared__ uint32_t bestp[256];
  __shared__ float    wred[4];

  const int tid  = threadIdx.x;
  const int lane = tid & 63;
  const int w    = tid >> 6;
  const int lane15 = lane & 15;

  // e2 -> LDS
  e2s[tid]       = e2p_g[tid];
  e2s[tid + 256] = e2p_g[tid + 256];

  // stage X tile (256 pixels x 64 dims) -> LDS in A-fragment order; fp32 ||x||^2
  const int bimg = blockIdx.x >> 4;        // 16 blocks per image
  const int hw0  = (blockIdx.x & 15) << 8;
  const float* latb = lat + (size_t)bimg * (VQ_D * VQ_HW) + hw0;
  float x2 = 0.f;
  {
    const int rt = tid >> 4, ll = tid & 15;
    #pragma unroll
    for (int i = 0; i < 32; ++i) {
      const int d0 = i * 2;
      const float v0 = latb[(d0    ) * VQ_HW + tid];
      const float v1 = latb[(d0 + 1) * VQ_HW + tid];
      x2 = fmaf(v0, v0, fmaf(v1, v1, x2));
      float2 f2; f2.x = v0; f2.y = v1;
      __hip_bfloat162 bb = __float22bfloat162_rn(f2);
      const int kh = d0 >> 5, quad = (d0 >> 3) & 3, j = d0 & 7;
      const int lf = quad * 16 + ll;       // A-frag: m = lane&15, k = quad*8+j
      a_frag[(((rt * 2 + kh) * 64 + lf) * 16 + j * 2) >> 2] = *(const uint32_t*)&bb;
    }
  }

  // prefetch first B fragments BEFORE the barrier: the barrier's vmcnt drain
  // completes them into VGPRs while the staging loads drain anyway.
  const bf16x8* bfr = (const bf16x8*)bfrag_g;   // fragment (ct,kh): bfr[(ct*2+kh)*64+lane]
  bf16x8 b0 = bfr[0 * 64 + lane];
  bf16x8 b1 = bfr[1 * 64 + lane];

  __syncthreads();

  // resident A fragments: 4 row-tiles (64 pixels) per wave
  bf16x8 af[4][2];
  #pragma unroll
  for (int rt = 0; rt < 4; ++rt)
    #pragma unroll
    for (int kh = 0; kh < 2; ++kh)
      af[rt][kh] = *(const bf16x8*)&a_frag[(((w * 4 + rt) * 2 + kh) * 64 + lane) * 4];

  float mins[4][4];
  #pragma unroll
  for (int rt = 0; rt < 4; ++rt)
    #pragma unroll
    for (int r = 0; r < 4; ++r) mins[rt][r] = 3.0e38f;

  // barrier-free K-loop over 32 code-tiles, depth-1 register prefetch
  #pragma unroll 4
  for (int ct = 0; ct < 32; ++ct) {
    const int ctn = (ct < 31) ? ct + 1 : 31;
    bf16x8 n0 = bfr[(ctn * 2 + 0) * 64 + lane];
    bf16x8 n1 = bfr[(ctn * 2 + 1) * 64 + lane];

    const float e2v = e2s[ct * 16 + lane15];
    const uint32_t ucode = (uint32_t)(ct * 16 + lane15);
    f32x4 acc[4];
    #pragma unroll
    for (int rt = 0; rt < 4; ++rt) {
      acc[rt] = (f32x4)(0.f);
      acc[rt] = __builtin_amdgcn_mfma_f32_16x16x32_bf16(af[rt][0], b0, acc[rt], 0, 0, 0);
      acc[rt] = __builtin_amdgcn_mfma_f32_16x16x32_bf16(af[rt][1], b1, acc[rt], 0, 0, 0);
    }
    #pragma unroll
    for (int rt = 0; rt < 4; ++rt)
      #pragma unroll
      for (int r = 0; r < 4; ++r) {
        const float s = fmaf(-2.f, acc[rt][r], e2v);
        const uint32_t pk = (__float_as_uint(s) & 0xFFFFFE00u) | ucode;
        mins[rt][r] = fminf(mins[rt][r], __uint_as_float(pk));
      }
    b0 = n0; b1 = n1;
  }

  // argmin across the 16 columns of each quad (C: col=lane&15, row=quad*4+r)
  #pragma unroll
  for (int off = 1; off < 16; off <<= 1)
    #pragma unroll
    for (int rt = 0; rt < 4; ++rt)
      #pragma unroll
      for (int r = 0; r < 4; ++r) {
        const float o = __shfl_xor(mins[rt][r], off, 64);
        mins[rt][r] = fminf(mins[rt][r], o);
      }
  const int quad = lane >> 4;
  if (lane15 == 0) {
    #pragma unroll
    for (int rt = 0; rt < 4; ++rt)
      #pragma unroll
      for (int r = 0; r < 4; ++r)
        bestp[(w * 4 + rt) * 16 + quad * 4 + r] = __float_as_uint(mins[rt][r]);
  }
  __syncthreads();

  // per-pixel epilogue: unpack code + min score; gather (float4) + write
  const uint32_t u = bestp[tid];
  const int code = (int)(u & 511u);
  const float smin = __uint_as_float(u & 0xFFFFFE00u) - 0.5f;
  float lossc = x2 + smin;                 // ||x - q||^2 for this pixel

  const float4* q4 = (const float4*)(emb + code * VQ_D);   // L2/L1-hot gather
  float* outp = out + (size_t)bimg * (VQ_D * VQ_HW) + hw0 + tid;
  #pragma unroll
  for (int i = 0; i < 16; ++i) {
    const float4 qv = q4[i];
    outp[(i * 4 + 0) * VQ_HW] = qv.x;
    outp[(i * 4 + 1) * VQ_HW] = qv.y;
    outp[(i * 4 + 2) * VQ_HW] = qv.z;
    outp[(i * 4 + 3) * VQ_HW] = qv.w;
  }

  #pragma unroll
  for (int off = 32; off > 0; off >>= 1) lossc += __shfl_down(lossc, off, 64);
  if (lane == 0) wred[w] = lossc;
  __syncthreads();
  if (tid == 0) partial[blockIdx.x] = wred[0] + wred[1] + wred[2] + wred[3];
}

__global__ __launch_bounds__(64) void vq_loss_kernel(
    const float* __restrict__ partial, float* __restrict__ loss_out)
{
  const int tid = threadIdx.x;
  float s = 0.f;
  #pragma unroll
  for (int i = 0; i < 8; ++i) s += partial[tid + i * 64];
  #pragma unroll
  for (int off = 32; off > 0; off >>= 1) s += __shfl_down(s, off, 64);
  if (tid == 0) *loss_out = 1.25f * s / (float)VQ_ELEMS;
}

extern "C" void kernel_launch(void* const* d_in, const int* in_sizes, int n_in,
                              void* d_out, int out_size, void* d_ws, size_t ws_size,
                              hipStream_t stream) {
  const float* lat = (const float*)d_in[0];
  const float* emb = (const float*)d_in[1];
  float* out = (float*)d_out;

  uint32_t* bfrag = (uint32_t*)d_ws;
  float* e2p      = (float*)((char*)d_ws + 65536);
  float* partial  = (float*)((char*)d_ws + 67584);

  vq_prep<<<17, 256, 0, stream>>>(emb, bfrag, e2p);
  vq_main<<<VQ_N / 256, 256, 0, stream>>>(lat, emb, bfrag, e2p, out, partial);
  vq_loss_kernel<<<1, 64, 0, stream>>>(partial, out + (size_t)VQ_ELEMS);
}

// Round 4
// 103.151 us; speedup vs baseline: 2.0027x; 1.0053x over previous
//
#include <hip/hip_runtime.h>
#include <hip/hip_bf16.h>

// VQ-VAE quantizer, MI355X. bf16-MFMA distance GEMM, direct-to-register
// A-fragments (no A LDS, no staging barrier), 1024 blocks for occupancy.
// latents: [B=32, D=64, H=64, W=64] fp32 ; embedding: [K=512, D=64] fp32
// out: quantized [B,D,H,W] fp32 (8388608) then vq_loss scalar (1).
// loss = 1.25 * mean(||x||^2 + (||e||^2 - 2 x.e_best))

#define VQ_K 512
#define VQ_D 64
#define VQ_HW 4096
#define VQ_N 131072
#define VQ_ELEMS 8388608

typedef float f32x4 __attribute__((ext_vector_type(4)));
typedef __bf16 bf16x8 __attribute__((ext_vector_type(8)));

// ws layout (bytes):
//   [0,      65536) : codebook bf16 in B-fragment order (64 chunks of 1 KB)
//   [65536,  67584) : e2p[512] = ||e_k||^2 + 0.5
//   [67584,  71680) : loss partials[1024]

// ---- prep: bf16 codebook fragments + squared norms -------------------------
__global__ __launch_bounds__(256) void vq_prep(
    const float* __restrict__ emb, uint32_t* __restrict__ bfrag,
    float* __restrict__ e2p)
{
  const int tid = threadIdx.x;
  if (blockIdx.x < 16) {
    const int gid  = blockIdx.x * 256 + tid;     // 0..4095
    const int lane = gid & 63, ckh = gid >> 6;   // ckh = ct*2 + kh
    const int ct = ckh >> 1, kh = ckh & 1;
    const int code  = ct * 16 + (lane & 15);     // B-frag: n = lane&15
    const int dbase = kh * 32 + (lane >> 4) * 8; // k = kh*32 + quad*8 + j
    const float* src = emb + code * VQ_D + dbase;
    uint32_t wds[4];
    #pragma unroll
    for (int jj = 0; jj < 4; ++jj) {
      float2 f2; f2.x = src[2 * jj]; f2.y = src[2 * jj + 1];
      __hip_bfloat162 bb = __float22bfloat162_rn(f2);
      wds[jj] = *(const uint32_t*)&bb;
    }
    uint4 v; v.x = wds[0]; v.y = wds[1]; v.z = wds[2]; v.w = wds[3];
    *(uint4*)&bfrag[gid * 4] = v;
  } else {
    for (int cc = tid; cc < VQ_K; cc += 256) {
      const float* src = emb + cc * VQ_D;
      float s = 0.f;
      #pragma unroll
      for (int d = 0; d < VQ_D; ++d) s = fmaf(src[d], src[d], s);
      e2p[cc] = s + 0.5f;   // +0.5 keeps all packed scores positive
    }
  }
}

// ---- main: MFMA scores + packed argmin + gather/write + loss ---------------
// 1024 blocks x 256 threads; block = 128 pixels; wave = 32 pixels (rt=2).
__global__ __launch_bounds__(256, 4) void vq_main(
    const float* __restrict__ lat, const float* __restrict__ emb,
    const uint32_t* __restrict__ bfrag_g, const float* __restrict__ e2p_g,
    float* __restrict__ out, float* __restrict__ partial)
{
  __shared__ float    e2s[VQ_K];     // 2 KB
  __shared__ uint32_t bestp[128];
  __shared__ float    wred[4];

  const int tid  = threadIdx.x;
  const int lane = tid & 63;
  const int w    = tid >> 6;
  const int lane15 = lane & 15;
  const int quad   = lane >> 4;

  // kick off first B-fragment prefetch immediately (overlaps A staging)
  const bf16x8* bfr = (const bf16x8*)bfrag_g;  // frag (ct,kh): bfr[(ct*2+kh)*64+lane]
  bf16x8 b0 = bfr[0 * 64 + lane];
  bf16x8 b1 = bfr[1 * 64 + lane];

  // e2 -> LDS (lgkmcnt path; doesn't disturb vmcnt prefetch pipeline)
  e2s[tid]       = e2p_g[tid];
  e2s[tid + 256] = e2p_g[tid + 256];

  // A fragments straight from global in MFMA-A layout + fp32 ||x||^2 partials.
  // Block = 128 pixels: bimg = blk/32, hw0 = (blk%32)*128.
  const int bimg = blockIdx.x >> 5;
  const int hw0  = (blockIdx.x & 31) << 7;
  const float* latb = lat + (size_t)bimg * (VQ_D * VQ_HW) + hw0;
  bf16x8 af[2][2];
  float x2part = 0.f;
  #pragma unroll
  for (int rt = 0; rt < 2; ++rt) {
    const int pix = (w * 2 + rt) * 16 + lane15;     // pixel within block
    const float* base = latb + pix + quad * 8 * VQ_HW;  // d = quad*8 + ...
    #pragma unroll
    for (int kh = 0; kh < 2; ++kh) {
      uint32_t wds[4];
      #pragma unroll
      for (int jj = 0; jj < 4; ++jj) {
        const float v0 = base[(kh * 32 + jj * 2    ) * VQ_HW];
        const float v1 = base[(kh * 32 + jj * 2 + 1) * VQ_HW];
        x2part = fmaf(v0, v0, fmaf(v1, v1, x2part));
        float2 f2; f2.x = v0; f2.y = v1;
        __hip_bfloat162 bb = __float22bfloat162_rn(f2);
        wds[jj] = *(const uint32_t*)&bb;
      }
      uint32_t tmp[4] = {wds[0], wds[1], wds[2], wds[3]};
      af[rt][kh] = *(const bf16x8*)tmp;
    }
  }

  __syncthreads();   // e2s visible (the only pre-loop barrier)

  float mins[2][4];
  #pragma unroll
  for (int rt = 0; rt < 2; ++rt)
    #pragma unroll
    for (int r = 0; r < 4; ++r) mins[rt][r] = 3.0e38f;

  // barrier-free K-loop over 32 code-tiles, depth-1 register prefetch
  #pragma unroll 4
  for (int ct = 0; ct < 32; ++ct) {
    const int ctn = (ct < 31) ? ct + 1 : 31;
    bf16x8 n0 = bfr[(ctn * 2 + 0) * 64 + lane];
    bf16x8 n1 = bfr[(ctn * 2 + 1) * 64 + lane];

    const float e2v = e2s[ct * 16 + lane15];
    const uint32_t ucode = (uint32_t)(ct * 16 + lane15);
    f32x4 acc[2];
    #pragma unroll
    for (int rt = 0; rt < 2; ++rt) {
      acc[rt] = (f32x4)(0.f);
      acc[rt] = __builtin_amdgcn_mfma_f32_16x16x32_bf16(af[rt][0], b0, acc[rt], 0, 0, 0);
      acc[rt] = __builtin_amdgcn_mfma_f32_16x16x32_bf16(af[rt][1], b1, acc[rt], 0, 0, 0);
    }
    #pragma unroll
    for (int rt = 0; rt < 2; ++rt)
      #pragma unroll
      for (int r = 0; r < 4; ++r) {
        const float s = fmaf(-2.f, acc[rt][r], e2v);
        const uint32_t pk = (__float_as_uint(s) & 0xFFFFFE00u) | ucode;
        mins[rt][r] = fminf(mins[rt][r], __uint_as_float(pk));
      }
    b0 = n0; b1 = n1;
  }

  // argmin across the 16 columns of each quad (C: col=lane&15, row=quad*4+r)
  #pragma unroll
  for (int off = 1; off < 16; off <<= 1)
    #pragma unroll
    for (int rt = 0; rt < 2; ++rt)
      #pragma unroll
      for (int r = 0; r < 4; ++r) {
        const float o = __shfl_xor(mins[rt][r], off, 64);
        mins[rt][r] = fminf(mins[rt][r], o);
      }
  if (lane15 == 0) {
    #pragma unroll
    for (int rt = 0; rt < 2; ++rt)
      #pragma unroll
      for (int r = 0; r < 4; ++r)
        bestp[(w * 2 + rt) * 16 + quad * 4 + r] = __float_as_uint(mins[rt][r]);
  }
  __syncthreads();

  // epilogue: 2 threads per pixel, each writes 32 of the 64 dims
  const int pixl = tid & 127;          // local pixel
  const int half = tid >> 7;           // 0: d<32, 1: d>=32
  const uint32_t u = bestp[pixl];
  const int code = (int)(u & 511u);
  float lossc = x2part;
  if (half == 0)
    lossc += __uint_as_float(u & 0xFFFFFE00u) - 0.5f;  // smin (has -||x||^2 folded via e2-2dot)

  const float4* q4 = (const float4*)(emb + code * VQ_D + half * 32);
  float* outp = out + (size_t)bimg * (VQ_D * VQ_HW) + hw0 + pixl + half * 32 * VQ_HW;
  #pragma unroll
  for (int i = 0; i < 8; ++i) {
    const float4 qv = q4[i];
    outp[(i * 4 + 0) * VQ_HW] = qv.x;
    outp[(i * 4 + 1) * VQ_HW] = qv.y;
    outp[(i * 4 + 2) * VQ_HW] = qv.z;
    outp[(i * 4 + 3) * VQ_HW] = qv.w;
  }

  #pragma unroll
  for (int off = 32; off > 0; off >>= 1) lossc += __shfl_down(lossc, off, 64);
  if (lane == 0) wred[w] = lossc;
  __syncthreads();
  if (tid == 0) partial[blockIdx.x] = wred[0] + wred[1] + wred[2] + wred[3];
}

__global__ __launch_bounds__(64) void vq_loss_kernel(
    const float* __restrict__ partial, float* __restrict__ loss_out)
{
  const int tid = threadIdx.x;
  float s = 0.f;
  #pragma unroll
  for (int i = 0; i < 16; ++i) s += partial[tid + i * 64];
  #pragma unroll
  for (int off = 32; off > 0; off >>= 1) s += __shfl_down(s, off, 64);
  if (tid == 0) *loss_out = 1.25f * s / (float)VQ_ELEMS;
}

extern "C" void kernel_launch(void* const* d_in, const int* in_sizes, int n_in,
                              void* d_out, int out_size, void* d_ws, size_t ws_size,
                              hipStream_t stream) {
  const float* lat = (const float*)d_in[0];
  const float* emb = (const float*)d_in[1];
  float* out = (float*)d_out;

  uint32_t* bfrag = (uint32_t*)d_ws;
  float* e2p      = (float*)((char*)d_ws + 65536);
  float* partial  = (float*)((char*)d_ws + 67584);

  vq_prep<<<17, 256, 0, stream>>>(emb, bfrag, e2p);
  vq_main<<<VQ_N / 128, 256, 0, stream>>>(lat, emb, bfrag, e2p, out, partial);
  vq_loss_kernel<<<1, 64, 0, stream>>>(partial, out + (size_t)VQ_ELEMS);
}